// Round 3
// baseline (220.238 us; speedup 1.0000x reference)
//
#include <hip/hip_runtime.h>

// Problem constants (from reference)
#define N_NODES 16384
#define D_EMB   128
#define LIST_CAP 1024          // max common neighbors (max degree ~200 incl. i==j)
#define BM_WORDS 512           // 16384 bits / 32 per compressed row
#define FLAG_OFF N_NODES       // int index of layout flag, right after used_flags
#define BM_OFF_BYTES (1 << 17) // bitmaps start at 128 KiB into ws
#define WS_NEEDED (BM_OFF_BYTES + (size_t)N_NODES * (BM_WORDS * 4)) // ~33.7 MB

// ---------------------------------------------------------------------------
// Pass 1: zero used-flags; block 0 also probes adjacency encoding.
// int32-bool: first 16384 words all in {0,1}. byte-bool: ~524 set bytes in
// the first 64KB at random offsets -> some word >1 w.p. ~1.
__global__ __launch_bounds__(256) void zero_probe_kernel(
    const unsigned int* __restrict__ words, int* __restrict__ flags)
{
    const int idx = blockIdx.x * 256 + threadIdx.x;  // grid 64 -> 16384 ints
    flags[idx] = 0;
    if (blockIdx.x == 0) {
        __shared__ int s_any;
        if (threadIdx.x == 0) s_any = 0;
        __syncthreads();
        int any = 0;
        for (int k = threadIdx.x; k < 16384; k += 256)
            if (words[k] > 1u) any = 1;
        if (any) atomicOr(&s_any, 1);
        __syncthreads();
        if (threadIdx.x == 0) flags[FLAG_OFF] = s_any;  // 1 => byte layout
    }
}

// Pass 2: mark rows referenced by any link endpoint (idempotent stores).
__global__ __launch_bounds__(256) void mark_kernel(
    const int* __restrict__ links, int* __restrict__ flags, int n_endpoints)
{
    const int k = blockIdx.x * 256 + threadIdx.x;
    if (k < n_endpoints) flags[links[k]] = 1;
}

// Pass 3: compress each USED row to a 512-word bitmap (the dominant pass:
// ~10.4k used rows x 64KB = ~680 MB HBM read, 21 MB write).
__global__ __launch_bounds__(256) void compress_kernel(
    const void* __restrict__ adjv, const int* __restrict__ flags,
    unsigned int* __restrict__ bm)
{
    const int r = blockIdx.x;
    if (!flags[r]) return;
    const int byte_layout = flags[FLAG_OFF];
    unsigned int* dst = bm + (size_t)r * BM_WORDS;

    if (!byte_layout) {
        // int32 per node: word w <- ints [32w, 32w+32) as 8 uint4
        const uint4* row = reinterpret_cast<const uint4*>(
            (const int*)adjv + (size_t)r * N_NODES);
#pragma unroll
        for (int half = 0; half < 2; ++half) {
            const int w = threadIdx.x * 2 + half;
            unsigned int bits = 0;
#pragma unroll
            for (int k = 0; k < 8; ++k) {
                const uint4 v = row[w * 8 + k];
                bits |= (v.x ? 1u : 0u) << (k * 4 + 0);
                bits |= (v.y ? 1u : 0u) << (k * 4 + 1);
                bits |= (v.z ? 1u : 0u) << (k * 4 + 2);
                bits |= (v.w ? 1u : 0u) << (k * 4 + 3);
            }
            dst[w] = bits;
        }
    } else {
        // byte per node: word w <- bytes [32w, 32w+32) as 2 uint4
        const uint4* row = reinterpret_cast<const uint4*>(
            (const unsigned char*)adjv + (size_t)r * N_NODES);
#pragma unroll
        for (int half = 0; half < 2; ++half) {
            const int w = threadIdx.x * 2 + half;
            unsigned int bits = 0;
#pragma unroll
            for (int q = 0; q < 2; ++q) {
                const uint4 v = row[w * 2 + q];
                const unsigned int arr[4] = {v.x, v.y, v.z, v.w};
#pragma unroll
                for (int a = 0; a < 4; ++a)
#pragma unroll
                    for (int bb = 0; bb < 4; ++bb)
                        bits |= ((((arr[a] >> (8 * bb)) & 0xFFu) ? 1u : 0u)
                                 << (q * 16 + a * 4 + bb));
            }
            dst[w] = bits;
        }
    }
}

// Pass 4: per link, AND two 2KB bitmaps (L2/L3-resident), extract CN
// indices, then write [product(128) | cn_sum(128)].
__global__ __launch_bounds__(256) void link_kernel(
    const int* __restrict__ links, const unsigned int* __restrict__ bm,
    const float* __restrict__ emb, float* __restrict__ out, int n_links)
{
    const int link = blockIdx.x;
    if (link >= n_links) return;
    const int i = links[2 * link];
    const int j = links[2 * link + 1];

    __shared__ int s_list[LIST_CAP];
    __shared__ int s_count;
    if (threadIdx.x == 0) s_count = 0;
    __syncthreads();

    const unsigned int* bi = bm + (size_t)i * BM_WORDS;
    const unsigned int* bj = bm + (size_t)j * BM_WORDS;
#pragma unroll
    for (int h = 0; h < 2; ++h) {
        const int w = h * 256 + threadIdx.x;
        unsigned int m = bi[w] & bj[w];
        while (m) {
            const int b = __ffs(m) - 1;
            m &= m - 1;
            const int pos = atomicAdd(&s_count, 1);
            if (pos < LIST_CAP) s_list[pos] = w * 32 + b;
        }
    }
    __syncthreads();

    int count = s_count;
    if (count > LIST_CAP) count = LIST_CAP;

    const int t = threadIdx.x;
    const size_t obase = (size_t)link * (2 * D_EMB);
    if (t < D_EMB) {
        out[obase + t] = emb[(size_t)i * D_EMB + t] * emb[(size_t)j * D_EMB + t];
    } else {
        const int d = t - D_EMB;
        float s = 0.0f;
        for (int c = 0; c < count; ++c)
            s += emb[(size_t)s_list[c] * D_EMB + d];
        out[obase + D_EMB + d] = s;
    }
}

// ---------------------------------------------------------------------------
// Fallback (ws too small): R2 direct kernel — reads both full rows per link.
__global__ __launch_bounds__(256) void detect_layout_kernel(
    const unsigned int* __restrict__ words, int* __restrict__ flag)
{
    __shared__ int s_any;
    if (threadIdx.x == 0) s_any = 0;
    __syncthreads();
    int any = 0;
    for (int k = threadIdx.x; k < 16384; k += 256)
        if (words[k] > 1u) any = 1;
    if (any) atomicOr(&s_any, 1);
    __syncthreads();
    if (threadIdx.x == 0) *flag = s_any;
}

__global__ __launch_bounds__(256) void ncn_direct(
    const int* __restrict__ links, const void* __restrict__ adjv,
    const float* __restrict__ emb, float* __restrict__ out,
    const int* __restrict__ flag, int n_links)
{
    const int link = blockIdx.x;
    if (link >= n_links) return;
    const int i = links[2 * link];
    const int j = links[2 * link + 1];

    __shared__ int s_list[LIST_CAP];
    __shared__ int s_count;
    if (threadIdx.x == 0) s_count = 0;
    __syncthreads();

    const int byte_layout = flag ? flag[0] : 0;
    if (byte_layout) {
        const uint4* rowi = reinterpret_cast<const uint4*>(
            (const unsigned char*)adjv + (size_t)i * N_NODES);
        const uint4* rowj = reinterpret_cast<const uint4*>(
            (const unsigned char*)adjv + (size_t)j * N_NODES);
#pragma unroll
        for (int c = 0; c < 4; ++c) {
            const int idx = c * 256 + threadIdx.x;
            const uint4 a = rowi[idx];
            const uint4 b = rowj[idx];
            unsigned int m[4] = {a.x & b.x, a.y & b.y, a.z & b.z, a.w & b.w};
            if (m[0] | m[1] | m[2] | m[3]) {
                const int base = idx * 16;
#pragma unroll
                for (int w = 0; w < 4; ++w) {
                    unsigned int v = m[w];
                    if (!v) continue;
#pragma unroll
                    for (int b8 = 0; b8 < 4; ++b8) {
                        if ((v >> (8 * b8)) & 0xFFu) {
                            int pos = atomicAdd(&s_count, 1);
                            if (pos < LIST_CAP) s_list[pos] = base + w * 4 + b8;
                        }
                    }
                }
            }
        }
    } else {
        const uint4* rowi = reinterpret_cast<const uint4*>(
            (const int*)adjv + (size_t)i * N_NODES);
        const uint4* rowj = reinterpret_cast<const uint4*>(
            (const int*)adjv + (size_t)j * N_NODES);
#pragma unroll
        for (int c = 0; c < 16; ++c) {
            const int idx = c * 256 + threadIdx.x;
            const uint4 a = rowi[idx];
            const uint4 b = rowj[idx];
            const int base = idx * 4;
            if (a.x & b.x) { int p = atomicAdd(&s_count, 1); if (p < LIST_CAP) s_list[p] = base + 0; }
            if (a.y & b.y) { int p = atomicAdd(&s_count, 1); if (p < LIST_CAP) s_list[p] = base + 1; }
            if (a.z & b.z) { int p = atomicAdd(&s_count, 1); if (p < LIST_CAP) s_list[p] = base + 2; }
            if (a.w & b.w) { int p = atomicAdd(&s_count, 1); if (p < LIST_CAP) s_list[p] = base + 3; }
        }
    }
    __syncthreads();

    int count = s_count;
    if (count > LIST_CAP) count = LIST_CAP;

    const int t = threadIdx.x;
    const size_t obase = (size_t)link * (2 * D_EMB);
    if (t < D_EMB) {
        out[obase + t] = emb[(size_t)i * D_EMB + t] * emb[(size_t)j * D_EMB + t];
    } else {
        const int d = t - D_EMB;
        float s = 0.0f;
        for (int c = 0; c < count; ++c)
            s += emb[(size_t)s_list[c] * D_EMB + d];
        out[obase + D_EMB + d] = s;
    }
}

extern "C" void kernel_launch(void* const* d_in, const int* in_sizes, int n_in,
                              void* d_out, int out_size, void* d_ws, size_t ws_size,
                              hipStream_t stream) {
    const int* links = (const int*)d_in[0];     // int32 [n_links][2]
    const void* adj = d_in[1];                  // bool matrix (encoding probed)
    const float* emb = (const float*)d_in[2];   // fp32 [N_NODES][D_EMB]
    float* out = (float*)d_out;

    const int n_links = in_sizes[0] / 2;

    if (ws_size >= WS_NEEDED) {
        int* flags = (int*)d_ws;
        unsigned int* bm = (unsigned int*)((char*)d_ws + BM_OFF_BYTES);
        zero_probe_kernel<<<N_NODES / 256, 256, 0, stream>>>(
            (const unsigned int*)adj, flags);
        mark_kernel<<<(2 * n_links + 255) / 256, 256, 0, stream>>>(
            links, flags, 2 * n_links);
        compress_kernel<<<N_NODES, 256, 0, stream>>>(adj, flags, bm);
        link_kernel<<<n_links, 256, 0, stream>>>(links, bm, emb, out, n_links);
    } else {
        int* flag = (ws_size >= sizeof(int)) ? (int*)d_ws : nullptr;
        if (flag) detect_layout_kernel<<<1, 256, 0, stream>>>(
            (const unsigned int*)adj, flag);
        ncn_direct<<<n_links, 256, 0, stream>>>(links, adj, emb, out, flag, n_links);
    }
}

// Round 4
// 176.854 us; speedup vs baseline: 1.2453x; 1.2453x over previous
//
#include <hip/hip_runtime.h>

// Problem constants (from reference)
#define N_NODES 16384
#define D_EMB   128
#define LIST_CAP 1024          // max common neighbors (max degree ~200 incl. i==j)
#define BM_WORDS 512           // 16384 bits / 32 per compressed row
#define FLAG_OFF N_NODES       // int index of layout flag, right after used_flags
#define BM_OFF_BYTES (1 << 17) // bitmaps start at 128 KiB into ws
#define WS_NEEDED (BM_OFF_BYTES + (size_t)N_NODES * (BM_WORDS * 4)) // ~33.7 MB

// ---------------------------------------------------------------------------
// Pass 1: zero used-flags; block 0 also probes adjacency encoding.
__global__ __launch_bounds__(256) void zero_probe_kernel(
    const unsigned int* __restrict__ words, int* __restrict__ flags)
{
    const int idx = blockIdx.x * 256 + threadIdx.x;  // grid 64 -> 16384 ints
    flags[idx] = 0;
    if (blockIdx.x == 0) {
        __shared__ int s_any;
        if (threadIdx.x == 0) s_any = 0;
        __syncthreads();
        int any = 0;
        for (int k = threadIdx.x; k < 16384; k += 256)
            if (words[k] > 1u) any = 1;
        if (any) atomicOr(&s_any, 1);
        __syncthreads();
        if (threadIdx.x == 0) flags[FLAG_OFF] = s_any;  // 1 => byte layout
    }
}

// Pass 2: mark rows referenced by any link endpoint (idempotent stores).
__global__ __launch_bounds__(256) void mark_kernel(
    const int* __restrict__ links, int* __restrict__ flags, int n_endpoints)
{
    const int k = blockIdx.x * 256 + threadIdx.x;
    if (k < n_endpoints) flags[links[k]] = 1;
}

// Pass 3: compress each USED row to a 512-word bitmap.
// COALESCED: chunk c, thread t loads uint4 at c*256+t (lane-contiguous),
// computes a 4-bit nibble, LDS-packs 8 nibbles -> 1 bitmap word.
__global__ __launch_bounds__(256) void compress_kernel(
    const void* __restrict__ adjv, const int* __restrict__ flags,
    unsigned int* __restrict__ bm)
{
    const int r = blockIdx.x;
    if (!flags[r]) return;
    const int byte_layout = flags[FLAG_OFF];
    unsigned int* dst = bm + (size_t)r * BM_WORDS;
    const int t = threadIdx.x;

    __shared__ unsigned int s_nib[256];

    if (!byte_layout) {
        // int32 per node: row = 4096 uint4; 16 chunks of 256.
        const uint4* row = reinterpret_cast<const uint4*>(
            (const int*)adjv + (size_t)r * N_NODES);
#pragma unroll
        for (int c = 0; c < 16; ++c) {
            const uint4 v = row[c * 256 + t];           // nodes [(c*256+t)*4, +4)
            unsigned int nib = (v.x ? 1u : 0u) | (v.y ? 2u : 0u)
                             | (v.z ? 4u : 0u) | (v.w ? 8u : 0u);
            s_nib[t] = nib;
            __syncthreads();
            if (t < 32) {
                unsigned int bits = 0;
#pragma unroll
                for (int q = 0; q < 8; ++q)
                    bits |= s_nib[t * 8 + q] << (4 * q);
                dst[c * 32 + t] = bits;                 // word covers nodes [c*1024+32t, +32)
            }
            __syncthreads();
        }
    } else {
        // byte per node: row = 1024 uint4; 4 chunks of 256; 16 nodes/thread.
        const uint4* row = reinterpret_cast<const uint4*>(
            (const unsigned char*)adjv + (size_t)r * N_NODES);
#pragma unroll
        for (int c = 0; c < 4; ++c) {
            const uint4 v = row[c * 256 + t];           // nodes [(c*256+t)*16, +16)
            const unsigned int arr[4] = {v.x, v.y, v.z, v.w};
            unsigned int half = 0;
#pragma unroll
            for (int a = 0; a < 4; ++a)
#pragma unroll
                for (int bb = 0; bb < 4; ++bb)
                    half |= ((((arr[a] >> (8 * bb)) & 0xFFu) ? 1u : 0u)
                             << (a * 4 + bb));
            s_nib[t] = half;                            // 16 bits valid
            __syncthreads();
            if (t < 128) {
                unsigned int bits = s_nib[t * 2] | (s_nib[t * 2 + 1] << 16);
                dst[c * 128 + t] = bits;
            }
            __syncthreads();
        }
    }
}

// Pass 4: per link, AND two 2KB bitmaps (cache-resident), extract CN
// indices, then write [product(128) | cn_sum(128)].
__global__ __launch_bounds__(256) void link_kernel(
    const int* __restrict__ links, const unsigned int* __restrict__ bm,
    const float* __restrict__ emb, float* __restrict__ out, int n_links)
{
    const int link = blockIdx.x;
    if (link >= n_links) return;
    const int i = links[2 * link];
    const int j = links[2 * link + 1];

    __shared__ int s_list[LIST_CAP];
    __shared__ int s_count;
    if (threadIdx.x == 0) s_count = 0;
    __syncthreads();

    const unsigned int* bi = bm + (size_t)i * BM_WORDS;
    const unsigned int* bj = bm + (size_t)j * BM_WORDS;
#pragma unroll
    for (int h = 0; h < 2; ++h) {
        const int w = h * 256 + threadIdx.x;
        unsigned int m = bi[w] & bj[w];
        while (m) {
            const int b = __ffs(m) - 1;
            m &= m - 1;
            const int pos = atomicAdd(&s_count, 1);
            if (pos < LIST_CAP) s_list[pos] = w * 32 + b;
        }
    }
    __syncthreads();

    int count = s_count;
    if (count > LIST_CAP) count = LIST_CAP;

    const int t = threadIdx.x;
    const size_t obase = (size_t)link * (2 * D_EMB);
    if (t < D_EMB) {
        out[obase + t] = emb[(size_t)i * D_EMB + t] * emb[(size_t)j * D_EMB + t];
    } else {
        const int d = t - D_EMB;
        float s = 0.0f;
        for (int c = 0; c < count; ++c)
            s += emb[(size_t)s_list[c] * D_EMB + d];
        out[obase + D_EMB + d] = s;
    }
}

// ---------------------------------------------------------------------------
// Fallback (ws too small): direct kernel — reads both full rows per link.
__global__ __launch_bounds__(256) void detect_layout_kernel(
    const unsigned int* __restrict__ words, int* __restrict__ flag)
{
    __shared__ int s_any;
    if (threadIdx.x == 0) s_any = 0;
    __syncthreads();
    int any = 0;
    for (int k = threadIdx.x; k < 16384; k += 256)
        if (words[k] > 1u) any = 1;
    if (any) atomicOr(&s_any, 1);
    __syncthreads();
    if (threadIdx.x == 0) *flag = s_any;
}

__global__ __launch_bounds__(256) void ncn_direct(
    const int* __restrict__ links, const void* __restrict__ adjv,
    const float* __restrict__ emb, float* __restrict__ out,
    const int* __restrict__ flag, int n_links)
{
    const int link = blockIdx.x;
    if (link >= n_links) return;
    const int i = links[2 * link];
    const int j = links[2 * link + 1];

    __shared__ int s_list[LIST_CAP];
    __shared__ int s_count;
    if (threadIdx.x == 0) s_count = 0;
    __syncthreads();

    const int byte_layout = flag ? flag[0] : 0;
    if (byte_layout) {
        const uint4* rowi = reinterpret_cast<const uint4*>(
            (const unsigned char*)adjv + (size_t)i * N_NODES);
        const uint4* rowj = reinterpret_cast<const uint4*>(
            (const unsigned char*)adjv + (size_t)j * N_NODES);
#pragma unroll
        for (int c = 0; c < 4; ++c) {
            const int idx = c * 256 + threadIdx.x;
            const uint4 a = rowi[idx];
            const uint4 b = rowj[idx];
            unsigned int m[4] = {a.x & b.x, a.y & b.y, a.z & b.z, a.w & b.w};
            if (m[0] | m[1] | m[2] | m[3]) {
                const int base = idx * 16;
#pragma unroll
                for (int w = 0; w < 4; ++w) {
                    unsigned int v = m[w];
                    if (!v) continue;
#pragma unroll
                    for (int b8 = 0; b8 < 4; ++b8) {
                        if ((v >> (8 * b8)) & 0xFFu) {
                            int pos = atomicAdd(&s_count, 1);
                            if (pos < LIST_CAP) s_list[pos] = base + w * 4 + b8;
                        }
                    }
                }
            }
        }
    } else {
        const uint4* rowi = reinterpret_cast<const uint4*>(
            (const int*)adjv + (size_t)i * N_NODES);
        const uint4* rowj = reinterpret_cast<const uint4*>(
            (const int*)adjv + (size_t)j * N_NODES);
#pragma unroll
        for (int c = 0; c < 16; ++c) {
            const int idx = c * 256 + threadIdx.x;
            const uint4 a = rowi[idx];
            const uint4 b = rowj[idx];
            const int base = idx * 4;
            if (a.x & b.x) { int p = atomicAdd(&s_count, 1); if (p < LIST_CAP) s_list[p] = base + 0; }
            if (a.y & b.y) { int p = atomicAdd(&s_count, 1); if (p < LIST_CAP) s_list[p] = base + 1; }
            if (a.z & b.z) { int p = atomicAdd(&s_count, 1); if (p < LIST_CAP) s_list[p] = base + 2; }
            if (a.w & b.w) { int p = atomicAdd(&s_count, 1); if (p < LIST_CAP) s_list[p] = base + 3; }
        }
    }
    __syncthreads();

    int count = s_count;
    if (count > LIST_CAP) count = LIST_CAP;

    const int t = threadIdx.x;
    const size_t obase = (size_t)link * (2 * D_EMB);
    if (t < D_EMB) {
        out[obase + t] = emb[(size_t)i * D_EMB + t] * emb[(size_t)j * D_EMB + t];
    } else {
        const int d = t - D_EMB;
        float s = 0.0f;
        for (int c = 0; c < count; ++c)
            s += emb[(size_t)s_list[c] * D_EMB + d];
        out[obase + D_EMB + d] = s;
    }
}

extern "C" void kernel_launch(void* const* d_in, const int* in_sizes, int n_in,
                              void* d_out, int out_size, void* d_ws, size_t ws_size,
                              hipStream_t stream) {
    const int* links = (const int*)d_in[0];     // int32 [n_links][2]
    const void* adj = d_in[1];                  // bool matrix (encoding probed)
    const float* emb = (const float*)d_in[2];   // fp32 [N_NODES][D_EMB]
    float* out = (float*)d_out;

    const int n_links = in_sizes[0] / 2;

    if (ws_size >= WS_NEEDED) {
        int* flags = (int*)d_ws;
        unsigned int* bm = (unsigned int*)((char*)d_ws + BM_OFF_BYTES);
        zero_probe_kernel<<<N_NODES / 256, 256, 0, stream>>>(
            (const unsigned int*)adj, flags);
        mark_kernel<<<(2 * n_links + 255) / 256, 256, 0, stream>>>(
            links, flags, 2 * n_links);
        compress_kernel<<<N_NODES, 256, 0, stream>>>(adj, flags, bm);
        link_kernel<<<n_links, 256, 0, stream>>>(links, bm, emb, out, n_links);
    } else {
        int* flag = (ws_size >= sizeof(int)) ? (int*)d_ws : nullptr;
        if (flag) detect_layout_kernel<<<1, 256, 0, stream>>>(
            (const unsigned int*)adj, flag);
        ncn_direct<<<n_links, 256, 0, stream>>>(links, adj, emb, out, flag, n_links);
    }
}